// Round 8
// baseline (188.945 us; speedup 1.0000x reference)
//
#include <hip/hip_runtime.h>

typedef __attribute__((ext_vector_type(8))) short bf16x8;
typedef __attribute__((ext_vector_type(4))) float f32x4;

#define HWSZ 65536
#define WSW_OFF 0
#define ZP_OFF  73728
#define XT_OFF  131072

__device__ inline unsigned to_bf16u(float f) {
    union { float f; unsigned u; } c; c.f = f;
    unsigned u = c.u;
    return (u + 0x7fffu + ((u >> 16) & 1u)) >> 16;   // round-nearest-even
}

// Weights fp32 [co][ci][9] -> bf16 LINEAR wsw [chunk][kpos][co][ci32]; also zero the zpage
__global__ void wcvt(const float* __restrict__ wgt, char* __restrict__ ws) {
    if (blockIdx.x == 0 && threadIdx.x < 32)
        ((unsigned*)(ws + ZP_OFF))[threadIdx.x] = 0;
    unsigned short* wsw = (unsigned short*)(ws + WSW_OFF);
    int idx = blockIdx.x * 256 + threadIdx.x;       // 36864 total
    int co   = idx / 576;
    int rem  = idx - co * 576;
    int ci   = rem / 9;
    int kpos = rem - ci * 9;
    unsigned short v = (unsigned short)to_bf16u(wgt[idx]);
    int chunk = ci >> 5, cil = ci & 31;
    wsw[((chunk * 9 + kpos) * 64 + co) * 32 + cil] = v;
}

// x fp32 NCHW -> bf16 channels-last xt[b][pix][octet-slot], column-swizzle baked in.
__global__ __launch_bounds__(256) void xcvt(const float* __restrict__ x, char* __restrict__ ws) {
    char* xt = ws + XT_OFF;
    const int tid = threadIdx.x;
    const int p = tid & 31, o = tid >> 5;
    const int pix = blockIdx.x * 32 + p;
    const int b = blockIdx.y;
    const int w = pix & 255;
    const float* src = x + ((size_t)b * 64 + o * 8) * HWSZ + pix;
    float v[8];
    #pragma unroll
    for (int k = 0; k < 8; ++k) v[k] = src[(size_t)k * HWSZ];
    unsigned u[4];
    #pragma unroll
    for (int k = 0; k < 4; ++k)
        u[k] = to_bf16u(v[2 * k]) | (to_bf16u(v[2 * k + 1]) << 16);
    int slot = o ^ (((w + 1) >> 1) & 3);   // XOR stays in o's half: chunk c bytes [c*64, c*64+64)
    *(uint4*)(xt + (size_t)(b * HWSZ + pix) * 128 + slot * 16) = (uint4){u[0], u[1], u[2], u[3]};
}

__global__ __launch_bounds__(256, 2) void maskconv_mfma(
    const char* __restrict__ ws, const int* __restrict__ mask,
    const float* __restrict__ bias, float* __restrict__ out)
{
    __shared__ unsigned short xs[624 * 32];   // 39936 B: [pixel 18x34][ci32], swizzled

    const int tid  = threadIdx.x;
    const int lane = tid & 63;
    const int wv   = tid >> 6;          // wave 0..3
    const int l15  = lane & 15;
    const int l4   = lane >> 4;
    const int pil  = lane >> 2;         // pixel-in-instruction 0..15
    const int slot = lane & 3;

    const int t  = blockIdx.x;          // 128 tiles: 8 w x 16 h
    const int tw = (t & 7) * 32;
    const int th = (t >> 3) * 16;
    const int b  = blockIdx.y;

    char* xsb = (char*)xs;
    const unsigned short* wsw = (const unsigned short*)(ws + WSW_OFF);
    const int hl = wv * 4;              // wave's first local output row

    f32x4 acc[8][4];
    #pragma unroll
    for (int f = 0; f < 8; ++f)
        #pragma unroll
        for (int j = 0; j < 4; ++j)
            acc[f][j] = (f32x4){0.f, 0.f, 0.f, 0.f};

    // stage: compute per-lane source offsets inline (no live register arrays)
    auto stage_x = [&](int c) {
        #pragma unroll
        for (int q = 0; q < 10; ++q) {
            int i = wv + 4 * q;
            if (i < 39) {               // wave-uniform
                int pi = i * 16 + pil;
                int r   = pi / 34;
                int lcv = pi - r * 34;
                int gr = th - 1 + r;
                int gc = tw - 1 + lcv;
                bool inb = (pi < 612) & ((unsigned)gr < 256u) & ((unsigned)gc < 256u);
                unsigned off = inb
                    ? (unsigned)(XT_OFF + (unsigned)((b * HWSZ) + (gr << 8) + gc) * 128u + slot * 16)
                    : (unsigned)(ZP_OFF + slot * 16);
                const char* g = ws + off + c * 64;
                unsigned short* l = xs + i * 512;
                __builtin_amdgcn_global_load_lds(
                    (const __attribute__((address_space(1))) void*)(const void*)g,
                    (__attribute__((address_space(3))) void*)(void*)l, 16, 0, 0);
            }
        }
    };

    // weights straight from global (L2-broadcast, linear layout)
    auto do_mfma = [&](int c) {
        const unsigned short* wc = wsw + c * 18432;
        #pragma unroll
        for (int kh = 0; kh < 3; ++kh) {
            #pragma unroll
            for (int kw = 0; kw < 3; ++kw) {
                const int kpos = kh * 3 + kw;
                bf16x8 bfrag[4];
                #pragma unroll
                for (int j = 0; j < 4; ++j)
                    bfrag[j] = *(const bf16x8*)(wc + (kpos * 64 + j * 16 + l15) * 32 + l4 * 8);
                #pragma unroll
                for (int f = 0; f < 8; ++f) {
                    int lc = (f & 1) * 16 + l15 + kw;
                    int r  = hl + (f >> 1) + kh;
                    int s  = (lc >> 1) & 3;
                    bf16x8 afrag = *(const bf16x8*)(xsb + (r * 34 + lc) * 64 + ((l4 ^ s) << 4));
                    #pragma unroll
                    for (int j = 0; j < 4; ++j)
                        acc[f][j] = __builtin_amdgcn_mfma_f32_16x16x32_bf16(
                            afrag, bfrag[j], acc[f][j], 0, 0, 0);
                }
            }
        }
    };

    stage_x(0);
    __syncthreads();            // drains vmcnt: xs chunk0 ready
    do_mfma(0);
    __syncthreads();            // done reading chunk0
    stage_x(1);
    __syncthreads();
    do_mfma(1);

    // ---- epilogue: bias (fp32) + mask, paired float4 stores ----
    const int* mb = mask + (size_t)b * HWSZ;
    float bv[4];
    #pragma unroll
    for (int j = 0; j < 4; ++j) bv[j] = bias[j * 16 + l15];

    #pragma unroll
    for (int fp = 0; fp < 4; ++fp) {
        int h   = th + hl + fp;
        int wq0 = tw + l4 * 4;
        int4 mv0 = *(const int4*)(mb + h * 256 + wq0);
        int4 mv1 = *(const int4*)(mb + h * 256 + wq0 + 16);
        float m00 = (float)mv0.x, m01 = (float)mv0.y, m02 = (float)mv0.z, m03 = (float)mv0.w;
        float m10 = (float)mv1.x, m11 = (float)mv1.y, m12 = (float)mv1.z, m13 = (float)mv1.w;
        #pragma unroll
        for (int j = 0; j < 4; ++j) {
            int co = j * 16 + l15;
            float* obase = out + (((size_t)(b * 64 + co)) << 16) + h * 256;
            f32x4 a0 = acc[2 * fp][j];
            f32x4 a1 = acc[2 * fp + 1][j];
            float4 o0, o1;
            o0.x = (a0.x + bv[j]) * m00;
            o0.y = (a0.y + bv[j]) * m01;
            o0.z = (a0.z + bv[j]) * m02;
            o0.w = (a0.w + bv[j]) * m03;
            o1.x = (a1.x + bv[j]) * m10;
            o1.y = (a1.y + bv[j]) * m11;
            o1.z = (a1.z + bv[j]) * m12;
            o1.w = (a1.w + bv[j]) * m13;
            *(float4*)(obase + wq0) = o0;
            *(float4*)(obase + wq0 + 16) = o1;
        }
    }
}

extern "C" void kernel_launch(void* const* d_in, const int* in_sizes, int n_in,
                              void* d_out, int out_size, void* d_ws, size_t ws_size,
                              hipStream_t stream) {
    const float* x    = (const float*)d_in[0];
    const int*   mask = (const int*)d_in[1];
    const float* wgt  = (const float*)d_in[2];
    const float* bias = (const float*)d_in[3];
    float* out = (float*)d_out;
    char* ws = (char*)d_ws;     // uses XT_OFF + 64 MiB = ~64.2 MiB of ws

    wcvt<<<dim3(144), dim3(256), 0, stream>>>(wgt, ws);
    xcvt<<<dim3(2048, 8), dim3(256), 0, stream>>>(x, ws);
    maskconv_mfma<<<dim3(128, 8), dim3(256), 0, stream>>>(ws, mask, bias, out);
}

// Round 10
// 113.308 us; speedup vs baseline: 1.6675x; 1.6675x over previous
//
#include <hip/hip_runtime.h>

typedef __attribute__((ext_vector_type(8))) short bf16x8;
typedef __attribute__((ext_vector_type(4))) float f32x4;

#define HWSZ 65536
#define WSW_OFF 0
#define ZP_OFF  73728
#define XT_OFF  131072

__device__ inline unsigned to_bf16u(float f) {
    union { float f; unsigned u; } c; c.f = f;
    unsigned u = c.u;
    return (u + 0x7fffu + ((u >> 16) & 1u)) >> 16;   // round-nearest-even
}

// Weights fp32 [co][ci][9] -> bf16 swizzled wsw [coh][chunk][kpos][co32][4 slot][8]
__global__ void wcvt(const float* __restrict__ wgt, char* __restrict__ ws) {
    if (blockIdx.x == 0 && threadIdx.x < 32)
        ((unsigned*)(ws + ZP_OFF))[threadIdx.x] = 0;
    unsigned short* wsw = (unsigned short*)(ws + WSW_OFF);
    int idx = blockIdx.x * 256 + threadIdx.x;       // 36864 total
    int co   = idx / 576;
    int rem  = idx - co * 576;
    int ci   = rem / 9;
    int kpos = rem - ci * 9;
    unsigned short v = (unsigned short)to_bf16u(wgt[idx]);
    int coh = co >> 5, col = co & 31;
    int chunk = ci >> 5, cil = ci & 31;
    int slot = (cil >> 3) ^ ((col >> 1) & 3);
    wsw[(((coh * 2 + chunk) * 9 + kpos) * 32 + col) * 32 + slot * 8 + (cil & 7)] = v;
}

// x fp32 NCHW -> bf16 channels-last xt[b][pix][octet-slot], column-swizzle baked in.
__global__ __launch_bounds__(256) void xcvt(const float* __restrict__ x, char* __restrict__ ws) {
    char* xt = ws + XT_OFF;
    const int tid = threadIdx.x;
    const int p = tid & 31, o = tid >> 5;
    const int pix = blockIdx.x * 32 + p;
    const int b = blockIdx.y;
    const int w = pix & 255;
    const float* src = x + ((size_t)b * 64 + o * 8) * HWSZ + pix;
    float v[8];
    #pragma unroll
    for (int k = 0; k < 8; ++k) v[k] = src[(size_t)k * HWSZ];
    unsigned u[4];
    #pragma unroll
    for (int k = 0; k < 4; ++k)
        u[k] = to_bf16u(v[2 * k]) | (to_bf16u(v[2 * k + 1]) << 16);
    int slot = o ^ (((w + 1) >> 1) & 3);   // XOR stays within o's chunk-half
    *(uint4*)(xt + (size_t)(b * HWSZ + pix) * 128 + slot * 16) = (uint4){u[0], u[1], u[2], u[3]};
}

__global__ __launch_bounds__(256, 3) void maskconv_mfma(
    const char* __restrict__ ws, const int* __restrict__ mask,
    const float* __restrict__ bias, float* __restrict__ out)
{
    __shared__ unsigned short xs[352 * 32];   // 22528 B: [pixel 10x34 (+pad)][ci32], swizzled
    __shared__ unsigned short wl[9 * 32 * 32];// 18432 B: [kpos][co32][ci32], swizzled (1 chunk)

    const int tid  = threadIdx.x;
    const int lane = tid & 63;
    const int wv   = tid >> 6;          // wave 0..3 -> rows wv*2..wv*2+1
    const int l15  = lane & 15;
    const int l4   = lane >> 4;
    const int pil  = lane >> 2;         // pixel-in-instruction 0..15
    const int slot = lane & 3;

    const int bx  = blockIdx.x;         // 0..511: coh*256 + tile
    const int coh = bx >> 8;
    const int tile = bx & 255;          // 8 w-tiles x 32 h-tiles
    const int tw = (tile & 7) * 32;
    const int th = (tile >> 3) * 8;
    const int b  = blockIdx.y;

    char* xsb = (char*)xs;
    char* wlb = (char*)wl;
    const unsigned short* wsw = (const unsigned short*)(ws + WSW_OFF);

    f32x4 acc[4][2];
    #pragma unroll
    for (int f = 0; f < 4; ++f)
        #pragma unroll
        for (int j = 0; j < 2; ++j)
            acc[f][j] = (f32x4){0.f, 0.f, 0.f, 0.f};

    auto stage_x = [&](int c) {
        #pragma unroll
        for (int q = 0; q < 6; ++q) {
            int i = wv + 4 * q;
            if (i < 22) {               // wave-uniform
                int pi = i * 16 + pil;  // 0..351
                int r   = pi / 34;
                int lcv = pi - r * 34;
                int gr = th - 1 + r;
                int gc = tw - 1 + lcv;
                bool inb = (pi < 340) & ((unsigned)gr < 256u) & ((unsigned)gc < 256u);
                unsigned off = inb
                    ? (unsigned)(XT_OFF + (unsigned)((b * HWSZ) + (gr << 8) + gc) * 128u + slot * 16)
                    : (unsigned)(ZP_OFF + slot * 16);
                const char* g = ws + off + c * 64;
                unsigned short* l = xs + i * 512;
                __builtin_amdgcn_global_load_lds(
                    (const __attribute__((address_space(1))) void*)(const void*)g,
                    (__attribute__((address_space(3))) void*)(void*)l, 16, 0, 0);
            }
        }
    };

    auto stage_wl = [&](int c) {
        const unsigned short* base = wsw + (coh * 2 + c) * 9216;
        #pragma unroll
        for (int q = 0; q < 5; ++q) {
            int i = wv + 4 * q;
            if (i < 18) {
                const unsigned short* g = base + i * 512 + lane * 8;   // per-lane source!
                unsigned short* l = wl + i * 512;
                __builtin_amdgcn_global_load_lds(
                    (const __attribute__((address_space(1))) void*)(const void*)g,
                    (__attribute__((address_space(3))) void*)(void*)l, 16, 0, 0);
            }
        }
    };

    auto do_mfma = [&]() {
        #pragma unroll
        for (int kh = 0; kh < 3; ++kh) {
            #pragma unroll
            for (int kw = 0; kw < 3; ++kw) {
                const int kpos = kh * 3 + kw;
                bf16x8 bfrag[2];
                #pragma unroll
                for (int j = 0; j < 2; ++j) {
                    int col = j * 16 + l15;
                    int sl = l4 ^ ((col >> 1) & 3);
                    bfrag[j] = *(const bf16x8*)(wlb + (kpos * 32 + col) * 64 + (sl << 4));
                }
                #pragma unroll
                for (int f = 0; f < 4; ++f) {
                    int lc = (f & 1) * 16 + l15 + kw;
                    int r  = wv * 2 + (f >> 1) + kh;
                    int s  = (lc >> 1) & 3;
                    bf16x8 afrag = *(const bf16x8*)(xsb + (r * 34 + lc) * 64 + ((l4 ^ s) << 4));
                    #pragma unroll
                    for (int j = 0; j < 2; ++j)
                        acc[f][j] = __builtin_amdgcn_mfma_f32_16x16x32_bf16(
                            afrag, bfrag[j], acc[f][j], 0, 0, 0);
                }
            }
        }
    };

    stage_wl(0);
    stage_x(0);
    __syncthreads();            // drains vmcnt: xs+wl chunk0 ready
    do_mfma();
    __syncthreads();            // done reading chunk0
    stage_wl(1);
    stage_x(1);
    __syncthreads();
    do_mfma();

    // ---- epilogue: bias (fp32) + mask, paired float4 stores ----
    const int* mb = mask + (size_t)b * HWSZ;
    float bv[2];
    #pragma unroll
    for (int j = 0; j < 2; ++j) bv[j] = bias[coh * 32 + j * 16 + l15];

    #pragma unroll
    for (int rr = 0; rr < 2; ++rr) {
        int h   = th + wv * 2 + rr;
        int wq0 = tw + l4 * 4;
        int4 mv0 = *(const int4*)(mb + h * 256 + wq0);
        int4 mv1 = *(const int4*)(mb + h * 256 + wq0 + 16);
        float m00 = (float)mv0.x, m01 = (float)mv0.y, m02 = (float)mv0.z, m03 = (float)mv0.w;
        float m10 = (float)mv1.x, m11 = (float)mv1.y, m12 = (float)mv1.z, m13 = (float)mv1.w;
        #pragma unroll
        for (int j = 0; j < 2; ++j) {
            int co = coh * 32 + j * 16 + l15;
            float* obase = out + (((size_t)(b * 64 + co)) << 16) + h * 256;
            f32x4 a0 = acc[rr * 2 + 0][j];   // cols wq0..wq0+3
            f32x4 a1 = acc[rr * 2 + 1][j];   // cols wq0+16..+19
            float4 o0, o1;
            o0.x = (a0.x + bv[j]) * m00;
            o0.y = (a0.y + bv[j]) * m01;
            o0.z = (a0.z + bv[j]) * m02;
            o0.w = (a0.w + bv[j]) * m03;
            o1.x = (a1.x + bv[j]) * m10;
            o1.y = (a1.y + bv[j]) * m11;
            o1.z = (a1.z + bv[j]) * m12;
            o1.w = (a1.w + bv[j]) * m13;
            *(float4*)(obase + wq0) = o0;
            *(float4*)(obase + wq0 + 16) = o1;
        }
    }
}

extern "C" void kernel_launch(void* const* d_in, const int* in_sizes, int n_in,
                              void* d_out, int out_size, void* d_ws, size_t ws_size,
                              hipStream_t stream) {
    const float* x    = (const float*)d_in[0];
    const int*   mask = (const int*)d_in[1];
    const float* wgt  = (const float*)d_in[2];
    const float* bias = (const float*)d_in[3];
    float* out = (float*)d_out;
    char* ws = (char*)d_ws;     // uses XT_OFF + 64 MiB of ws

    wcvt<<<dim3(144), dim3(256), 0, stream>>>(wgt, ws);
    xcvt<<<dim3(2048, 8), dim3(256), 0, stream>>>(x, ws);
    maskconv_mfma<<<dim3(512, 8), dim3(256), 0, stream>>>(ws, mask, bias, out);
}